// Round 1
// baseline (2353.902 us; speedup 1.0000x reference)
//
#include <hip/hip_runtime.h>
#include <math.h>

#define Hh 512
#define Ww 512
#define WINP 128
#define KK 6

// ---------------- box (argmax) kernel ----------------
__global__ void box_kernel(const float* __restrict__ pred, int* __restrict__ box) {
    int tid = threadIdx.x;
    float best = -1.0f; int bidx = 0x7fffffff;
    for (int cand = tid; cand < 51 * 51; cand += 256) {
        int i = cand / 51, j = cand % 51;
        int y = i * 10, x = j * 10;
        float T = 0.f, Bv = 0.f;
#pragma unroll
        for (int k = 0; k < KK; ++k) {
            T  += pred[((k * 3 + 0) * Hh + y) * Ww + x];
            Bv += pred[((k * 3 + 2) * Hh + y) * Ww + x];
        }
        float d = fabsf(1.0f - T - Bv / 6.0f);
        if (d > best || (d == best && cand < bidx)) { best = d; bidx = cand; }
    }
    __shared__ float sv[256];
    __shared__ int   si[256];
    sv[tid] = best; si[tid] = bidx;
    __syncthreads();
    for (int s = 128; s > 0; s >>= 1) {
        if (tid < s) {
            if (sv[tid + s] > sv[tid] || (sv[tid + s] == sv[tid] && si[tid + s] < si[tid])) {
                sv[tid] = sv[tid + s]; si[tid] = si[tid + s];
            }
        }
        __syncthreads();
    }
    if (tid == 0) {
        int idx = si[0];
        int cy = (idx / 51) * 10, cx = (idx % 51) * 10;
        int yy = cy - 64; yy = yy < 0 ? 0 : (yy > Hh - WINP ? Hh - WINP : yy);
        int xx = cx - 64; xx = xx < 0 ? 0 : (xx > Ww - WINP ? Ww - WINP : xx);
        box[0] = yy; box[1] = xx;
    }
}

// ---------------- copy pred_list -> out ----------------
__global__ void copy_kernel(const float4* __restrict__ src, float4* __restrict__ dst) {
    int i = blockIdx.x * 256 + threadIdx.x;
    dst[i] = src[i];
}

// ---------------- split conv (grouped, attention-modulated) ----------------
// grid: (4,4, 6k*3g*4chunk=72), block 256. Tile 32x32, 2x2 per thread, 8 oc per block.
__global__ __launch_bounds__(256) void split_conv_kernel(
    const float* __restrict__ feat, const float* __restrict__ pl,
    const float* __restrict__ w, const float* __restrict__ b,
    const int* __restrict__ box, float* __restrict__ fs)
{
    const int tid = threadIdx.x;
    const int bz = blockIdx.z;
    const int chunk = bz & 3;
    const int g = (bz >> 2) % 3;
    const int k = bz / 12;
    const int oc0 = chunk * 8;
    const int ty0 = blockIdx.y * 32, tx0 = blockIdx.x * 32;
    const int y1 = box[0], x1 = box[1];

    __shared__ float s_w[64 * 9 * 8];
    __shared__ float s_pred[34 * 34];
    __shared__ float s_in[34 * 34];

    // weights: s_w[(ic*9+t)*8 + j] = w[((g*32+oc0+j)*64 + ic)*9 + t]
    for (int idx = tid; idx < 64 * 9 * 8; idx += 256) {
        int j = idx & 7; int rest = idx >> 3; int t = rest % 9; int ic = rest / 9;
        s_w[idx] = w[((g * 32 + oc0 + j) * 64 + ic) * 9 + t];
    }
    for (int idx = tid; idx < 34 * 34; idx += 256) {
        int r = idx / 34, c = idx % 34;
        int py = ty0 - 1 + r, px = tx0 - 1 + c;
        float v = 0.f;
        if (py >= 0 && py < WINP && px >= 0 && px < WINP)
            v = pl[((k * 3 + g) * Hh + (y1 + py)) * Ww + (x1 + px)];
        s_pred[idx] = v;
    }
    __syncthreads();

    float acc[8][4];
#pragma unroll
    for (int j = 0; j < 8; ++j) { acc[j][0] = acc[j][1] = acc[j][2] = acc[j][3] = 0.f; }

    const int lr = (tid >> 4) * 2, lc = (tid & 15) * 2;

    for (int ic = 0; ic < 64; ++ic) {
        for (int idx = tid; idx < 34 * 34; idx += 256) {
            int r = idx / 34, c = idx % 34;
            int py = ty0 - 1 + r, px = tx0 - 1 + c;
            float v = 0.f;
            if (py >= 0 && py < WINP && px >= 0 && px < WINP)
                v = feat[((k * 64 + ic) * Hh + (y1 + py)) * Ww + (x1 + px)] * s_pred[idx];
            s_in[idx] = v;
        }
        __syncthreads();
        const float* wp0 = &s_w[ic * 72];
#pragma unroll
        for (int dy = 0; dy < 3; ++dy)
#pragma unroll
        for (int dx = 0; dx < 3; ++dx) {
            int basei = (lr + dy) * 34 + (lc + dx);
            float v00 = s_in[basei],      v01 = s_in[basei + 1];
            float v10 = s_in[basei + 34], v11 = s_in[basei + 35];
            const float* wp = wp0 + (dy * 3 + dx) * 8;
#pragma unroll
            for (int j = 0; j < 8; ++j) {
                float wj = wp[j];
                acc[j][0] += wj * v00; acc[j][1] += wj * v01;
                acc[j][2] += wj * v10; acc[j][3] += wj * v11;
            }
        }
        __syncthreads();
    }
#pragma unroll
    for (int j = 0; j < 8; ++j) {
        int ch = g * 32 + oc0 + j;
        float bias = b[ch];
        float* op = &fs[(k * 96 + ch) * (WINP * WINP)];
        op[(ty0 + lr) * WINP + tx0 + lc]         = acc[j][0] + bias;
        op[(ty0 + lr) * WINP + tx0 + lc + 1]     = acc[j][1] + bias;
        op[(ty0 + lr + 1) * WINP + tx0 + lc]     = acc[j][2] + bias;
        op[(ty0 + lr + 1) * WINP + tx0 + lc + 1] = acc[j][3] + bias;
    }
}

// ---------------- combine: fs -> fcat (99ch) ----------------
__global__ void combine_kernel(const float* __restrict__ fs, const float* __restrict__ x,
                               const int* __restrict__ box, float* __restrict__ fcat)
{
    int t = blockIdx.x * 256 + threadIdx.x;   // < 35*16384
    int c = t >> 14;
    int pix = t & 16383;
    const int P = WINP * WINP;
    if (c < 32) {
        float f0v[6], f1v[6];
        float s0 = 0, s1 = 0, s2 = 0;
#pragma unroll
        for (int k = 0; k < 6; ++k) {
            float a0 = fs[(k * 96 + c) * P + pix];
            float a1 = fs[(k * 96 + 32 + c) * P + pix];
            float a2 = fs[(k * 96 + 64 + c) * P + pix];
            f0v[k] = a0; f1v[k] = a1;
            s0 += a0; s1 += a1; s2 += a2;
        }
        float fb = s2 / 6.0f;
        float t0 = s1 / 5.0f - s0;
#pragma unroll
        for (int k = 0; k < 6; ++k) {
            fcat[(k * 99 + c) * P + pix]      = t0 + 2.0f * f0v[k];
            fcat[(k * 99 + 32 + c) * P + pix] = s0 - f0v[k] + f1v[k];
            fcat[(k * 99 + 64 + c) * P + pix] = fb;
        }
    } else {
        int ch = c - 32;
        int y1 = box[0], x1 = box[1];
        int py = pix >> 7, px = pix & 127;
#pragma unroll
        for (int k = 0; k < 6; ++k) {
            fcat[(k * 99 + 96 + ch) * P + pix] =
                x[((k * 3 + ch) * Hh + y1 + py) * Ww + (x1 + px)];
        }
    }
}

// ---------------- merge convs ----------------
// grid: (4,4, 6k*8chunk=48), block 256.
template<int IC, bool LEAKY>
__global__ __launch_bounds__(256) void merge_conv_kernel(
    const float* __restrict__ in, const float* __restrict__ w,
    const float* __restrict__ b, float* __restrict__ out)
{
    const int tid = threadIdx.x;
    const int bz = blockIdx.z;
    const int chunk = bz & 7;
    const int k = bz >> 3;
    const int oc0 = chunk * 8;
    const int ty0 = blockIdx.y * 32, tx0 = blockIdx.x * 32;
    const int P = WINP * WINP;

    __shared__ float s_w[IC * 9 * 8];
    __shared__ float s_in[34 * 34];

    for (int idx = tid; idx < IC * 9 * 8; idx += 256) {
        int j = idx & 7; int rest = idx >> 3; int t = rest % 9; int ic = rest / 9;
        s_w[idx] = w[((oc0 + j) * IC + ic) * 9 + t];
    }

    float acc[8][4];
#pragma unroll
    for (int j = 0; j < 8; ++j) { acc[j][0] = acc[j][1] = acc[j][2] = acc[j][3] = 0.f; }

    const int lr = (tid >> 4) * 2, lc = (tid & 15) * 2;
    __syncthreads();

    for (int ic = 0; ic < IC; ++ic) {
        for (int idx = tid; idx < 34 * 34; idx += 256) {
            int r = idx / 34, c = idx % 34;
            int py = ty0 - 1 + r, px = tx0 - 1 + c;
            float v = 0.f;
            if (py >= 0 && py < WINP && px >= 0 && px < WINP)
                v = in[(k * IC + ic) * P + py * WINP + px];
            s_in[idx] = v;
        }
        __syncthreads();
        const float* wp0 = &s_w[ic * 72];
#pragma unroll
        for (int dy = 0; dy < 3; ++dy)
#pragma unroll
        for (int dx = 0; dx < 3; ++dx) {
            int basei = (lr + dy) * 34 + (lc + dx);
            float v00 = s_in[basei],      v01 = s_in[basei + 1];
            float v10 = s_in[basei + 34], v11 = s_in[basei + 35];
            const float* wp = wp0 + (dy * 3 + dx) * 8;
#pragma unroll
            for (int j = 0; j < 8; ++j) {
                float wj = wp[j];
                acc[j][0] += wj * v00; acc[j][1] += wj * v01;
                acc[j][2] += wj * v10; acc[j][3] += wj * v11;
            }
        }
        __syncthreads();
    }
#pragma unroll
    for (int j = 0; j < 8; ++j) {
        float bias = b[oc0 + j];
        float* op = &out[(k * 64 + oc0 + j) * P];
#pragma unroll
        for (int p = 0; p < 4; ++p) {
            float v = acc[j][p] + bias;
            if (LEAKY) v = (v >= 0.f) ? v : 0.2f * v;
            int py = ty0 + lr + (p >> 1), px = tx0 + lc + (p & 1);
            op[py * WINP + px] = v;
        }
    }
}

// ---------------- head conv + tanh + scatter ----------------
// grid: (4,4,6), block 256. Tiles cover [10,118) with masking.
__global__ __launch_bounds__(256) void head_kernel(
    const float* __restrict__ fm, const float* __restrict__ w,
    const float* __restrict__ b, const int* __restrict__ box,
    float* __restrict__ out)
{
    const int tid = threadIdx.x;
    const int k = blockIdx.z;
    const int ty0 = 10 + blockIdx.y * 32, tx0 = 10 + blockIdx.x * 32;
    const int y1 = box[0], x1 = box[1];
    const int P = WINP * WINP;

    __shared__ float s_w[64 * 9 * 3];
    __shared__ float s_in[34 * 34];

    for (int idx = tid; idx < 64 * 9 * 3; idx += 256) {
        int oc = idx % 3; int rest = idx / 3; int t = rest % 9; int ic = rest / 9;
        s_w[idx] = w[(oc * 64 + ic) * 9 + t];
    }

    float acc[3][4];
#pragma unroll
    for (int j = 0; j < 3; ++j) { acc[j][0] = acc[j][1] = acc[j][2] = acc[j][3] = 0.f; }

    const int lr = (tid >> 4) * 2, lc = (tid & 15) * 2;
    __syncthreads();

    for (int ic = 0; ic < 64; ++ic) {
        for (int idx = tid; idx < 34 * 34; idx += 256) {
            int r = idx / 34, c = idx % 34;
            int py = ty0 - 1 + r, px = tx0 - 1 + c;
            float v = 0.f;
            if (py >= 0 && py < WINP && px >= 0 && px < WINP)
                v = fm[(k * 64 + ic) * P + py * WINP + px];
            s_in[idx] = v;
        }
        __syncthreads();
        const float* wp0 = &s_w[ic * 27];
#pragma unroll
        for (int dy = 0; dy < 3; ++dy)
#pragma unroll
        for (int dx = 0; dx < 3; ++dx) {
            int basei = (lr + dy) * 34 + (lc + dx);
            float v00 = s_in[basei],      v01 = s_in[basei + 1];
            float v10 = s_in[basei + 34], v11 = s_in[basei + 35];
            const float* wp = wp0 + (dy * 3 + dx) * 3;
#pragma unroll
            for (int j = 0; j < 3; ++j) {
                float wj = wp[j];
                acc[j][0] += wj * v00; acc[j][1] += wj * v01;
                acc[j][2] += wj * v10; acc[j][3] += wj * v11;
            }
        }
        __syncthreads();
    }
#pragma unroll
    for (int j = 0; j < 3; ++j) {
        float bias = b[j];
#pragma unroll
        for (int p = 0; p < 4; ++p) {
            int py = ty0 + lr + (p >> 1), px = tx0 + lc + (p & 1);
            if (py < 118 && px < 118) {
                float v = (tanhf(acc[j][p] + bias) + 1.0f) * 0.5f;
                out[((k * 3 + j) * Hh + y1 + py) * Ww + (x1 + px)] = v;
            }
        }
    }
}

extern "C" void kernel_launch(void* const* d_in, const int* in_sizes, int n_in,
                              void* d_out, int out_size, void* d_ws, size_t ws_size,
                              hipStream_t stream)
{
    const float* x       = (const float*)d_in[0];
    const float* pred    = (const float*)d_in[1];
    const float* feat    = (const float*)d_in[2];
    const float* split_w = (const float*)d_in[3];
    const float* split_b = (const float*)d_in[4];
    const float* m1w     = (const float*)d_in[5];
    const float* m1b     = (const float*)d_in[6];
    const float* m2w     = (const float*)d_in[7];
    const float* m2b     = (const float*)d_in[8];
    const float* hw      = (const float*)d_in[9];
    const float* hb      = (const float*)d_in[10];
    float* out = (float*)d_out;

    int*   box = (int*)d_ws;
    float* A   = (float*)d_ws + 256;              // fs (6*96*128*128) / h1 (6*64*128*128)
    float* B   = A + 6 * 96 * 128 * 128;          // fcat (6*99*128*128) / fm (6*64*128*128)

    box_kernel<<<1, 256, 0, stream>>>(pred, box);
    copy_kernel<<<4608, 256, 0, stream>>>((const float4*)pred, (float4*)out);

    for (int it = 0; it < 2; ++it) {
        split_conv_kernel<<<dim3(4, 4, 72), 256, 0, stream>>>(feat, out, split_w, split_b, box, A);
        combine_kernel<<<2240, 256, 0, stream>>>(A, x, box, B);
        merge_conv_kernel<99, true><<<dim3(4, 4, 48), 256, 0, stream>>>(B, m1w, m1b, A);
        merge_conv_kernel<64, false><<<dim3(4, 4, 48), 256, 0, stream>>>(A, m2w, m2b, B);
        head_kernel<<<dim3(4, 4, 6), 256, 0, stream>>>(B, hw, hb, box, out);
    }
}

// Round 2
// 1675.962 us; speedup vs baseline: 1.4045x; 1.4045x over previous
//
#include <hip/hip_runtime.h>
#include <math.h>

#define Hh 512
#define Ww 512
#define WINP 128
#define PP (WINP * WINP)
#define KK 6

// conv tile geometry: 32 rows x 64 cols per block, halo 34 x 66, LDS stride 68
#define TH 32
#define TW 64
#define SROWS 34
#define SCOLS 66
#define SSTR 68
#define SELEMS (SROWS * SCOLS)  // 2244
#define PF_N 9                  // ceil(2244/256)

// ---------------- box (argmax) kernel ----------------
__global__ void box_kernel(const float* __restrict__ pred, int* __restrict__ box) {
    int tid = threadIdx.x;
    float best = -1.0f; int bidx = 0x7fffffff;
    for (int cand = tid; cand < 51 * 51; cand += 256) {
        int i = cand / 51, j = cand % 51;
        int y = i * 10, x = j * 10;
        float T = 0.f, Bv = 0.f;
#pragma unroll
        for (int k = 0; k < KK; ++k) {
            T  += pred[((k * 3 + 0) * Hh + y) * Ww + x];
            Bv += pred[((k * 3 + 2) * Hh + y) * Ww + x];
        }
        float d = fabsf(1.0f - T - Bv / 6.0f);
        if (d > best || (d == best && cand < bidx)) { best = d; bidx = cand; }
    }
    __shared__ float sv[256];
    __shared__ int   si[256];
    sv[tid] = best; si[tid] = bidx;
    __syncthreads();
    for (int s = 128; s > 0; s >>= 1) {
        if (tid < s) {
            if (sv[tid + s] > sv[tid] || (sv[tid + s] == sv[tid] && si[tid + s] < si[tid])) {
                sv[tid] = sv[tid + s]; si[tid] = si[tid + s];
            }
        }
        __syncthreads();
    }
    if (tid == 0) {
        int idx = si[0];
        int cy = (idx / 51) * 10, cx = (idx % 51) * 10;
        int yy = cy - 64; yy = yy < 0 ? 0 : (yy > Hh - WINP ? Hh - WINP : yy);
        int xx = cx - 64; xx = xx < 0 ? 0 : (xx > Ww - WINP ? Ww - WINP : xx);
        box[0] = yy; box[1] = xx;
    }
}

// ---------------- copy pred_list -> out ----------------
__global__ void copy_kernel(const float4* __restrict__ src, float4* __restrict__ dst) {
    int i = blockIdx.x * 256 + threadIdx.x;
    dst[i] = src[i];
}

// ---------------- split conv (grouped, attention-modulated) ----------------
// grid (2,4, 6k*3g*4chunk=72), block 256. Tile 32x64, micro 2x4, 8 oc/block.
__global__ __launch_bounds__(256) void split_conv_kernel(
    const float* __restrict__ feat, const float* __restrict__ pl,
    const float* __restrict__ w, const float* __restrict__ b,
    const int* __restrict__ box, float* __restrict__ fs)
{
    const int tid = threadIdx.x;
    const int bz = blockIdx.z;
    const int chunk = bz & 3;
    const int g = (bz >> 2) % 3;
    const int k = bz / 12;
    const int oc0 = chunk * 8;
    const int ty0 = blockIdx.y * TH, tx0 = blockIdx.x * TW;
    const int y1 = box[0], x1 = box[1];

    __shared__ float s_w[64 * 9 * 8];        // [(ic*9+t)*8 + j]
    __shared__ float s_in[SROWS * SSTR + 1]; // last slot = dummy for inactive lanes

    for (int idx = tid; idx < 64 * 9 * 8; idx += 256) {
        int j = idx & 7; int rest = idx >> 3; int t = rest % 9; int ic = rest / 9;
        s_w[idx] = w[((g * 32 + oc0 + j) * 64 + ic) * 9 + t];
    }

    // hoisted per-thread staging addressing + pred values (registers, no LDS plane)
    int offs[PF_N]; int lidx[PF_N]; float pv[PF_N];
    const float* plg = pl + (size_t)(k * 3 + g) * Hh * Ww;
#pragma unroll
    for (int i = 0; i < PF_N; ++i) {
        int idx = tid + i * 256;
        int off = -1; int li = SROWS * SSTR;
        if (idx < SELEMS) {
            int r = idx / SCOLS, c = idx - r * SCOLS;
            li = r * SSTR + c;
            int py = ty0 - 1 + r, px = tx0 - 1 + c;
            if (py >= 0 && py < WINP && px >= 0 && px < WINP)
                off = (y1 + py) * Ww + (x1 + px);
        }
        offs[i] = off; lidx[i] = li;
        float pvv = plg[off >= 0 ? off : 0];
        pv[i] = off >= 0 ? pvv : 0.f;
    }

    const float* featk = feat + (size_t)k * 64 * Hh * Ww;
    float pf[PF_N];
#pragma unroll
    for (int i = 0; i < PF_N; ++i) {                 // prefetch ic = 0
        float v = featk[offs[i] >= 0 ? offs[i] : 0];
        pf[i] = offs[i] >= 0 ? v : 0.f;
    }

    float acc[8][8];
#pragma unroll
    for (int j = 0; j < 8; ++j)
#pragma unroll
        for (int p = 0; p < 8; ++p) acc[j][p] = 0.f;

    const int tx = tid & 15, ty = tid >> 4;
    const int col0 = tx * 4, row0 = ty * 2;

    for (int ic = 0; ic < 64; ++ic) {
        __syncthreads();
#pragma unroll
        for (int i = 0; i < PF_N; ++i) s_in[lidx[i]] = pf[i] * pv[i];
        __syncthreads();
        if (ic + 1 < 64) {
            const float* fp = featk + (size_t)(ic + 1) * (Hh * Ww);
#pragma unroll
            for (int i = 0; i < PF_N; ++i) {          // prefetch next ic (overlaps compute)
                float v = fp[offs[i] >= 0 ? offs[i] : 0];
                pf[i] = offs[i] >= 0 ? v : 0.f;
            }
        }
        float in[4][6];
#pragma unroll
        for (int r = 0; r < 4; ++r) {
            const float* rp = &s_in[(row0 + r) * SSTR + col0];
            float4 a = *(const float4*)rp;
            float2 bq = *(const float2*)(rp + 4);
            in[r][0] = a.x; in[r][1] = a.y; in[r][2] = a.z; in[r][3] = a.w;
            in[r][4] = bq.x; in[r][5] = bq.y;
        }
        const float* wp0 = &s_w[ic * 72];
#pragma unroll
        for (int dy = 0; dy < 3; ++dy)
#pragma unroll
        for (int dx = 0; dx < 3; ++dx) {
            const float4* wv = (const float4*)(wp0 + (dy * 3 + dx) * 8);
            float4 w0 = wv[0], w1 = wv[1];
            float wj[8] = {w0.x, w0.y, w0.z, w0.w, w1.x, w1.y, w1.z, w1.w};
#pragma unroll
            for (int j = 0; j < 8; ++j)
#pragma unroll
            for (int r = 0; r < 2; ++r)
#pragma unroll
            for (int c = 0; c < 4; ++c)
                acc[j][r * 4 + c] += wj[j] * in[r + dy][c + dx];
        }
    }
#pragma unroll
    for (int j = 0; j < 8; ++j) {
        int ch = g * 32 + oc0 + j;
        float bias = b[ch];
        float* op = &fs[((size_t)k * 96 + ch) * PP];
#pragma unroll
        for (int r = 0; r < 2; ++r) {
            float4 o;
            o.x = acc[j][r * 4 + 0] + bias; o.y = acc[j][r * 4 + 1] + bias;
            o.z = acc[j][r * 4 + 2] + bias; o.w = acc[j][r * 4 + 3] + bias;
            *(float4*)&op[(ty0 + row0 + r) * WINP + tx0 + col0] = o;
        }
    }
}

// ---------------- combine: fs -> fcat (99ch) ----------------
__global__ void combine_kernel(const float* __restrict__ fs, const float* __restrict__ x,
                               const int* __restrict__ box, float* __restrict__ fcat)
{
    int t = blockIdx.x * 256 + threadIdx.x;   // < 35*16384
    int c = t >> 14;
    int pix = t & 16383;
    if (c < 32) {
        float f0v[6], f1v[6];
        float s0 = 0, s1 = 0, s2 = 0;
#pragma unroll
        for (int k = 0; k < 6; ++k) {
            float a0 = fs[(k * 96 + c) * PP + pix];
            float a1 = fs[(k * 96 + 32 + c) * PP + pix];
            float a2 = fs[(k * 96 + 64 + c) * PP + pix];
            f0v[k] = a0; f1v[k] = a1;
            s0 += a0; s1 += a1; s2 += a2;
        }
        float fb = s2 / 6.0f;
        float t0 = s1 / 5.0f - s0;
#pragma unroll
        for (int k = 0; k < 6; ++k) {
            fcat[(k * 99 + c) * PP + pix]      = t0 + 2.0f * f0v[k];
            fcat[(k * 99 + 32 + c) * PP + pix] = s0 - f0v[k] + f1v[k];
            fcat[(k * 99 + 64 + c) * PP + pix] = fb;
        }
    } else {
        int ch = c - 32;
        int y1 = box[0], x1 = box[1];
        int py = pix >> 7, px = pix & 127;
#pragma unroll
        for (int k = 0; k < 6; ++k) {
            fcat[(k * 99 + 96 + ch) * PP + pix] =
                x[((k * 3 + ch) * Hh + y1 + py) * Ww + (x1 + px)];
        }
    }
}

// ---------------- merge convs ----------------
// grid (2,4, 6k*16chunk=96), block 256. Tile 32x64, micro 2x4, 4 oc/block.
template<int IC, bool LEAKY>
__global__ __launch_bounds__(256) void merge_conv_kernel(
    const float* __restrict__ in, const float* __restrict__ w,
    const float* __restrict__ b, float* __restrict__ out)
{
    const int tid = threadIdx.x;
    const int bz = blockIdx.z;
    const int chunk = bz & 15;
    const int k = bz >> 4;
    const int oc0 = chunk * 4;
    const int ty0 = blockIdx.y * TH, tx0 = blockIdx.x * TW;

    __shared__ float s_w[IC * 9 * 4];        // [(ic*9+t)*4 + j]
    __shared__ float s_in[SROWS * SSTR + 1];

    for (int idx = tid; idx < IC * 36; idx += 256) {
        int j = idx & 3; int rest = idx >> 2; int t = rest % 9; int ic = rest / 9;
        s_w[idx] = w[((oc0 + j) * IC + ic) * 9 + t];
    }

    int offs[PF_N]; int lidx[PF_N];
#pragma unroll
    for (int i = 0; i < PF_N; ++i) {
        int idx = tid + i * 256;
        int off = -1; int li = SROWS * SSTR;
        if (idx < SELEMS) {
            int r = idx / SCOLS, c = idx - r * SCOLS;
            li = r * SSTR + c;
            int py = ty0 - 1 + r, px = tx0 - 1 + c;
            if (py >= 0 && py < WINP && px >= 0 && px < WINP)
                off = py * WINP + px;
        }
        offs[i] = off; lidx[i] = li;
    }

    const float* ink = in + (size_t)k * IC * PP;
    float pf[PF_N];
#pragma unroll
    for (int i = 0; i < PF_N; ++i) {
        float v = ink[offs[i] >= 0 ? offs[i] : 0];
        pf[i] = offs[i] >= 0 ? v : 0.f;
    }

    float acc[4][8];
#pragma unroll
    for (int j = 0; j < 4; ++j)
#pragma unroll
        for (int p = 0; p < 8; ++p) acc[j][p] = 0.f;

    const int tx = tid & 15, ty = tid >> 4;
    const int col0 = tx * 4, row0 = ty * 2;

    for (int ic = 0; ic < IC; ++ic) {
        __syncthreads();
#pragma unroll
        for (int i = 0; i < PF_N; ++i) s_in[lidx[i]] = pf[i];
        __syncthreads();
        if (ic + 1 < IC) {
            const float* fp = ink + (size_t)(ic + 1) * PP;
#pragma unroll
            for (int i = 0; i < PF_N; ++i) {
                float v = fp[offs[i] >= 0 ? offs[i] : 0];
                pf[i] = offs[i] >= 0 ? v : 0.f;
            }
        }
        float inp[4][6];
#pragma unroll
        for (int r = 0; r < 4; ++r) {
            const float* rp = &s_in[(row0 + r) * SSTR + col0];
            float4 a = *(const float4*)rp;
            float2 bq = *(const float2*)(rp + 4);
            inp[r][0] = a.x; inp[r][1] = a.y; inp[r][2] = a.z; inp[r][3] = a.w;
            inp[r][4] = bq.x; inp[r][5] = bq.y;
        }
        const float* wp0 = &s_w[ic * 36];
#pragma unroll
        for (int dy = 0; dy < 3; ++dy)
#pragma unroll
        for (int dx = 0; dx < 3; ++dx) {
            float4 w0 = *(const float4*)(wp0 + (dy * 3 + dx) * 4);
            float wj[4] = {w0.x, w0.y, w0.z, w0.w};
#pragma unroll
            for (int j = 0; j < 4; ++j)
#pragma unroll
            for (int r = 0; r < 2; ++r)
#pragma unroll
            for (int c = 0; c < 4; ++c)
                acc[j][r * 4 + c] += wj[j] * inp[r + dy][c + dx];
        }
    }
#pragma unroll
    for (int j = 0; j < 4; ++j) {
        float bias = b[oc0 + j];
        float* op = &out[((size_t)k * 64 + oc0 + j) * PP];
#pragma unroll
        for (int r = 0; r < 2; ++r) {
            float4 o;
            o.x = acc[j][r * 4 + 0] + bias; o.y = acc[j][r * 4 + 1] + bias;
            o.z = acc[j][r * 4 + 2] + bias; o.w = acc[j][r * 4 + 3] + bias;
            if (LEAKY) {
                o.x = o.x >= 0.f ? o.x : 0.2f * o.x;
                o.y = o.y >= 0.f ? o.y : 0.2f * o.y;
                o.z = o.z >= 0.f ? o.z : 0.2f * o.z;
                o.w = o.w >= 0.f ? o.w : 0.2f * o.w;
            }
            *(float4*)&op[(ty0 + row0 + r) * WINP + tx0 + col0] = o;
        }
    }
}

// ---------------- head conv + tanh + scatter ----------------
// grid (2,4,6), block 256. Tiles cover [10,138) clipped to <118.
__global__ __launch_bounds__(256) void head_kernel(
    const float* __restrict__ fm, const float* __restrict__ w,
    const float* __restrict__ b, const int* __restrict__ box,
    float* __restrict__ out)
{
    const int tid = threadIdx.x;
    const int k = blockIdx.z;
    const int ty0 = 10 + blockIdx.y * TH, tx0 = 10 + blockIdx.x * TW;
    const int y1 = box[0], x1 = box[1];

    __shared__ float s_w[64 * 9 * 3];        // [(ic*9+t)*3 + j]
    __shared__ float s_in[SROWS * SSTR + 1];

    for (int idx = tid; idx < 64 * 27; idx += 256) {
        int j = idx % 3; int rest = idx / 3; int t = rest % 9; int ic = rest / 9;
        s_w[idx] = w[(j * 64 + ic) * 9 + t];
    }

    int offs[PF_N]; int lidx[PF_N];
#pragma unroll
    for (int i = 0; i < PF_N; ++i) {
        int idx = tid + i * 256;
        int off = -1; int li = SROWS * SSTR;
        if (idx < SELEMS) {
            int r = idx / SCOLS, c = idx - r * SCOLS;
            li = r * SSTR + c;
            int py = ty0 - 1 + r, px = tx0 - 1 + c;
            if (py < WINP && px < WINP)        // lower bounds >= 9 always
                off = py * WINP + px;
        }
        offs[i] = off; lidx[i] = li;
    }

    const float* ink = fm + (size_t)k * 64 * PP;
    float pf[PF_N];
#pragma unroll
    for (int i = 0; i < PF_N; ++i) {
        float v = ink[offs[i] >= 0 ? offs[i] : 0];
        pf[i] = offs[i] >= 0 ? v : 0.f;
    }

    float acc[3][8];
#pragma unroll
    for (int j = 0; j < 3; ++j)
#pragma unroll
        for (int p = 0; p < 8; ++p) acc[j][p] = 0.f;

    const int tx = tid & 15, ty = tid >> 4;
    const int col0 = tx * 4, row0 = ty * 2;

    for (int ic = 0; ic < 64; ++ic) {
        __syncthreads();
#pragma unroll
        for (int i = 0; i < PF_N; ++i) s_in[lidx[i]] = pf[i];
        __syncthreads();
        if (ic + 1 < 64) {
            const float* fp = ink + (size_t)(ic + 1) * PP;
#pragma unroll
            for (int i = 0; i < PF_N; ++i) {
                float v = fp[offs[i] >= 0 ? offs[i] : 0];
                pf[i] = offs[i] >= 0 ? v : 0.f;
            }
        }
        float inp[4][6];
#pragma unroll
        for (int r = 0; r < 4; ++r) {
            const float* rp = &s_in[(row0 + r) * SSTR + col0];
            float4 a = *(const float4*)rp;
            float2 bq = *(const float2*)(rp + 4);
            inp[r][0] = a.x; inp[r][1] = a.y; inp[r][2] = a.z; inp[r][3] = a.w;
            inp[r][4] = bq.x; inp[r][5] = bq.y;
        }
        const float* wp0 = &s_w[ic * 27];
#pragma unroll
        for (int dy = 0; dy < 3; ++dy)
#pragma unroll
        for (int dx = 0; dx < 3; ++dx) {
            const float* wp = wp0 + (dy * 3 + dx) * 3;
            float w0 = wp[0], w1 = wp[1], w2 = wp[2];
#pragma unroll
            for (int r = 0; r < 2; ++r)
#pragma unroll
            for (int c = 0; c < 4; ++c) {
                float v = inp[r + dy][c + dx];
                acc[0][r * 4 + c] += w0 * v;
                acc[1][r * 4 + c] += w1 * v;
                acc[2][r * 4 + c] += w2 * v;
            }
        }
    }
#pragma unroll
    for (int j = 0; j < 3; ++j) {
        float bias = b[j];
#pragma unroll
        for (int r = 0; r < 2; ++r)
#pragma unroll
        for (int c = 0; c < 4; ++c) {
            int oy = ty0 + row0 + r, ox = tx0 + col0 + c;
            if (oy < 118 && ox < 118) {
                float v = (tanhf(acc[j][r * 4 + c] + bias) + 1.0f) * 0.5f;
                out[((k * 3 + j) * Hh + y1 + oy) * Ww + (x1 + ox)] = v;
            }
        }
    }
}

extern "C" void kernel_launch(void* const* d_in, const int* in_sizes, int n_in,
                              void* d_out, int out_size, void* d_ws, size_t ws_size,
                              hipStream_t stream)
{
    const float* x       = (const float*)d_in[0];
    const float* pred    = (const float*)d_in[1];
    const float* feat    = (const float*)d_in[2];
    const float* split_w = (const float*)d_in[3];
    const float* split_b = (const float*)d_in[4];
    const float* m1w     = (const float*)d_in[5];
    const float* m1b     = (const float*)d_in[6];
    const float* m2w     = (const float*)d_in[7];
    const float* m2b     = (const float*)d_in[8];
    const float* hw      = (const float*)d_in[9];
    const float* hb      = (const float*)d_in[10];
    float* out = (float*)d_out;

    int*   box = (int*)d_ws;
    float* A   = (float*)d_ws + 256;              // fs (6*96*P) / h1 (6*64*P)
    float* B   = A + 6 * 96 * PP;                 // fcat (6*99*P) / fm (6*64*P)

    box_kernel<<<1, 256, 0, stream>>>(pred, box);
    copy_kernel<<<4608, 256, 0, stream>>>((const float4*)pred, (float4*)out);

    for (int it = 0; it < 2; ++it) {
        split_conv_kernel<<<dim3(2, 4, 72), 256, 0, stream>>>(feat, out, split_w, split_b, box, A);
        combine_kernel<<<2240, 256, 0, stream>>>(A, x, box, B);
        merge_conv_kernel<99, true><<<dim3(2, 4, 96), 256, 0, stream>>>(B, m1w, m1b, A);
        merge_conv_kernel<64, false><<<dim3(2, 4, 96), 256, 0, stream>>>(A, m2w, m2b, B);
        head_kernel<<<dim3(2, 4, 6), 256, 0, stream>>>(B, hw, hb, box, out);
    }
}

// Round 3
// 698.845 us; speedup vs baseline: 3.3683x; 2.3982x over previous
//
#include <hip/hip_runtime.h>
#include <math.h>

typedef __attribute__((ext_vector_type(8))) short short8_t;
typedef __attribute__((ext_vector_type(4))) float f32x4;

#define Hh 512
#define Ww 512
#define IMG (Hh * Ww)
#define WINP 128
#define PP (WINP * WINP)

__device__ __forceinline__ unsigned short f2bf(float f) {
    unsigned int u = __builtin_bit_cast(unsigned int, f);
    u += 0x7fffu + ((u >> 16) & 1u);
    return (unsigned short)(u >> 16);
}
__device__ __forceinline__ float bf2f(unsigned short h) {
    unsigned int u = ((unsigned int)h) << 16;
    return __builtin_bit_cast(float, u);
}

// ---------------- box (argmax) ----------------
__global__ void box_kernel(const float* __restrict__ pred, int* __restrict__ box) {
    int tid = threadIdx.x;
    float best = -1.0f; int bidx = 0x7fffffff;
    for (int cand = tid; cand < 51 * 51; cand += 256) {
        int i = cand / 51, j = cand % 51;
        int y = i * 10, x = j * 10;
        float T = 0.f, Bv = 0.f;
#pragma unroll
        for (int k = 0; k < 6; ++k) {
            T  += pred[((k * 3 + 0) * Hh + y) * Ww + x];
            Bv += pred[((k * 3 + 2) * Hh + y) * Ww + x];
        }
        float d = fabsf(1.0f - T - Bv / 6.0f);
        if (d > best || (d == best && cand < bidx)) { best = d; bidx = cand; }
    }
    __shared__ float sv[256];
    __shared__ int   si[256];
    sv[tid] = best; si[tid] = bidx;
    __syncthreads();
    for (int s = 128; s > 0; s >>= 1) {
        if (tid < s) {
            if (sv[tid + s] > sv[tid] || (sv[tid + s] == sv[tid] && si[tid + s] < si[tid])) {
                sv[tid] = sv[tid + s]; si[tid] = si[tid + s];
            }
        }
        __syncthreads();
    }
    if (tid == 0) {
        int idx = si[0];
        int cy = (idx / 51) * 10, cx = (idx % 51) * 10;
        int yy = cy - 64; yy = yy < 0 ? 0 : (yy > Hh - WINP ? Hh - WINP : yy);
        int xx = cx - 64; xx = xx < 0 ? 0 : (xx > Ww - WINP ? Ww - WINP : xx);
        box[0] = yy; box[1] = xx;
    }
}

// ---------------- copy pred -> out ----------------
__global__ void copy_kernel(const float4* __restrict__ src, float4* __restrict__ dst) {
    int i = blockIdx.x * 256 + threadIdx.x;
    dst[i] = src[i];
}

// ---------------- weight pre-swizzle into B-fragment order ----------------
// WF fragment: lane l holds B[k=(l>>4)*8+j][n=l&15], j=0..7
// layout: split[g][kc2][tap][nf2] | m1[half][kc4][tap][nf2] | m2[half][kc2][tap][nf2] | head[kc2][tap]
// frag units of 512 ushorts. totals: 108 | 144 | 72 | 18 frags.
__global__ void prep_weights(const float* __restrict__ sw, const float* __restrict__ m1w,
                             const float* __restrict__ m2w, const float* __restrict__ hw,
                             unsigned short* __restrict__ WF)
{
    int idx = blockIdx.x * 256 + threadIdx.x;   // < 175104 exactly
    int j = idx & 7;
    int lane = (idx >> 3) & 63;
    int frag = idx >> 9;
    int n16 = lane & 15;
    int ko = (lane >> 4) * 8 + j;
    float v = 0.f;
    if (frag < 108) {
        int g = frag / 36; int r = frag % 36; int kc = r / 18; r %= 18; int tap = r / 2; int nf = r & 1;
        int oc = g * 32 + nf * 16 + n16; int ic = kc * 32 + ko;
        v = sw[(oc * 64 + ic) * 9 + tap];
    } else if (frag < 252) {
        int r = frag - 108; int half = r / 72; r %= 72; int kc = r / 18; r %= 18; int tap = r / 2; int nf = r & 1;
        int oc = half * 32 + nf * 16 + n16; int ic = kc * 32 + ko;
        if (ic < 99) v = m1w[(oc * 99 + ic) * 9 + tap];
    } else if (frag < 324) {
        int r = frag - 252; int half = r / 36; r %= 36; int kc = r / 18; r %= 18; int tap = r / 2; int nf = r & 1;
        int oc = half * 32 + nf * 16 + n16; int ic = kc * 32 + ko;
        v = m2w[(oc * 64 + ic) * 9 + tap];
    } else {
        int r = frag - 324; int kc = r / 9; int tap = r % 9;
        int ic = kc * 32 + ko;
        if (n16 < 3) v = hw[(n16 * 64 + ic) * 9 + tap];
    }
    WF[idx] = f2bf(v);
}

// ---------------- feat patch -> channel-last bf16 ----------------
__global__ void prep_featcl(const float* __restrict__ feat, const int* __restrict__ box,
                            unsigned short* __restrict__ featcl)
{
    int row = blockIdx.x;   // 0..127
    int k = blockIdx.y;
    int t = threadIdx.x;
    int y1 = box[0], x1 = box[1];
    __shared__ unsigned short s[128 * 64];
    for (int i = 0; i < 32; ++i) {
        int idx = t + i * 256;
        int ic = idx >> 7, c = idx & 127;
        s[c * 64 + ic] = f2bf(feat[((size_t)(k * 64 + ic) * Hh + y1 + row) * Ww + x1 + c]);
    }
    __syncthreads();
    if (t < 128) {
        unsigned short* dst = &featcl[((size_t)k * 16384 + row * 128 + t) * 64];
        for (int i = 0; i < 8; ++i)
            *(short8_t*)&dst[i * 8] = *(short8_t*)&s[t * 64 + i * 8];
    }
}

// ---------------- split conv MFMA (grouped, attention-modulated) ----------------
// grid (64 tiles, 18 = k*3+g). block 256 = 4 waves; wave = 4 Mfrags(rows) x 2 Nfrags.
__global__ __launch_bounds__(256) void split_mfma(
    const unsigned short* __restrict__ featcl, const float* __restrict__ pl,
    const unsigned short* __restrict__ WF, const float* __restrict__ sb,
    const int* __restrict__ box, unsigned short* __restrict__ fscl)
{
    const int tid = threadIdx.x;
    const int l = tid & 63, w = tid >> 6;
    const int T = blockIdx.x;
    const int k = blockIdx.y / 3, g = blockIdx.y % 3;
    const int ty0 = (T >> 3) * 16, tx0 = (T & 7) * 16;
    const int y1 = box[0], x1 = box[1];

    __shared__ __align__(16) unsigned short s_a[10368];  // 18*18*32
    __shared__ __align__(16) unsigned short s_b[9216];   // 9*2*512

    f32x4 acc[4][2];
#pragma unroll
    for (int mf = 0; mf < 4; ++mf)
#pragma unroll
        for (int nf = 0; nf < 2; ++nf) acc[mf][nf] = (f32x4){0.f, 0.f, 0.f, 0.f};

    const float* plg = pl + (size_t)(k * 3 + g) * IMG + (size_t)y1 * Ww + x1;
    const unsigned short* fck = featcl + (size_t)k * 16384 * 64;

    for (int kc = 0; kc < 2; ++kc) {
        __syncthreads();
#pragma unroll
        for (int i = 0; i < 6; ++i) {
            int s = tid + i * 256;
            if (s < 1296) {
                int pxs = s >> 2, q = s & 3;
                int r = pxs / 18, c = pxs - r * 18;
                int py = ty0 - 1 + r, px = tx0 - 1 + c;
                short8_t o;
                if (py >= 0 && py < WINP && px >= 0 && px < WINP) {
                    float pv = plg[py * Ww + px];
                    short8_t f = *(const short8_t*)&fck[(size_t)(py * WINP + px) * 64 + kc * 32 + q * 8];
#pragma unroll
                    for (int e = 0; e < 8; ++e) o[e] = (short)f2bf(bf2f((unsigned short)f[e]) * pv);
                } else {
#pragma unroll
                    for (int e = 0; e < 8; ++e) o[e] = 0;
                }
                *(short8_t*)&s_a[(r * 18 + c) * 32 + q * 8] = o;
            }
        }
        {
            const unsigned short* src = WF + (size_t)((g * 2 + kc) * 18) * 512;
#pragma unroll
            for (int i = 0; i < 5; ++i) {
                int cch = tid + i * 256;
                if (cch < 1152)
                    *(short8_t*)&s_b[cch * 8] = *(const short8_t*)&src[cch * 8];
            }
        }
        __syncthreads();
#pragma unroll
        for (int tap = 0; tap < 9; ++tap) {
            int dy = tap / 3, dx = tap % 3;
            short8_t a[4];
#pragma unroll
            for (int mf = 0; mf < 4; ++mf)
                a[mf] = *(const short8_t*)&s_a[((w * 4 + mf + dy) * 18 + (l & 15) + dx) * 32 + (l >> 4) * 8];
#pragma unroll
            for (int nf = 0; nf < 2; ++nf) {
                short8_t bfr = *(const short8_t*)&s_b[((tap * 2 + nf) * 64 + l) * 8];
#pragma unroll
                for (int mf = 0; mf < 4; ++mf)
                    acc[mf][nf] = __builtin_amdgcn_mfma_f32_16x16x32_bf16(a[mf], bfr, acc[mf][nf], 0, 0, 0);
            }
        }
    }
    __syncthreads();
    unsigned short* s_t = s_a;   // 256*32 = 8192 <= 10368
#pragma unroll
    for (int nf = 0; nf < 2; ++nf) {
        float bias = sb[g * 32 + nf * 16 + (l & 15)];
#pragma unroll
        for (int mf = 0; mf < 4; ++mf) {
            int row = w * 4 + mf;
#pragma unroll
            for (int r = 0; r < 4; ++r) {
                int col = (l >> 4) * 4 + r;
                s_t[(row * 16 + col) * 32 + nf * 16 + (l & 15)] = f2bf(acc[mf][nf][r] + bias);
            }
        }
    }
    __syncthreads();
    {
        int row = tid >> 4, col = tid & 15;
        size_t gpx = (size_t)(ty0 + row) * WINP + tx0 + col;
        unsigned short* dst = fscl + ((size_t)k * 16384 + gpx) * 96 + g * 32;
#pragma unroll
        for (int i = 0; i < 4; ++i)
            *(short8_t*)&dst[i * 8] = *(short8_t*)&s_t[tid * 32 + i * 8];
    }
}

// ---------------- k-sum planes: T0 = S1/5 - S0, S0, B2 = S2/6 ----------------
__global__ void reduce_kernel(const unsigned short* __restrict__ fscl, float* __restrict__ Scl)
{
    int tg = blockIdx.x * 256 + threadIdx.x;  // < 65536
    int px = tg >> 2, q = tg & 3;
    float s0[8], s1[8], s2[8];
#pragma unroll
    for (int e = 0; e < 8; ++e) { s0[e] = 0.f; s1[e] = 0.f; s2[e] = 0.f; }
#pragma unroll
    for (int k = 0; k < 6; ++k) {
        const unsigned short* p = &fscl[((size_t)k * 16384 + px) * 96 + q * 8];
        short8_t a0 = *(const short8_t*)&p[0];
        short8_t a1 = *(const short8_t*)&p[32];
        short8_t a2 = *(const short8_t*)&p[64];
#pragma unroll
        for (int e = 0; e < 8; ++e) {
            s0[e] += bf2f((unsigned short)a0[e]);
            s1[e] += bf2f((unsigned short)a1[e]);
            s2[e] += bf2f((unsigned short)a2[e]);
        }
    }
    float* d = &Scl[(size_t)px * 96 + q * 8];
#pragma unroll
    for (int e = 0; e < 8; ++e) {
        d[e]      = s1[e] * 0.2f - s0[e];
        d[32 + e] = s0[e];
        d[64 + e] = s2[e] * (1.f / 6.f);
    }
}

// ---------------- merge1 MFMA (fused fcat combine in A-staging) ----------------
// grid (64, 12 = k*2+half). IC padded to 128 (4 kchunks; kc3 = x channels + zeros).
__global__ __launch_bounds__(256) void merge1_mfma(
    const unsigned short* __restrict__ fscl, const float* __restrict__ Scl,
    const float* __restrict__ x, const unsigned short* __restrict__ WF,
    const float* __restrict__ m1b, const int* __restrict__ box,
    unsigned short* __restrict__ h1cl)
{
    const int tid = threadIdx.x;
    const int l = tid & 63, w = tid >> 6;
    const int T = blockIdx.x;
    const int k = blockIdx.y >> 1, half = blockIdx.y & 1;
    const int ty0 = (T >> 3) * 16, tx0 = (T & 7) * 16;
    const int y1 = box[0], x1 = box[1];

    __shared__ __align__(16) unsigned short s_a[10368];
    __shared__ __align__(16) unsigned short s_b[9216];

    f32x4 acc[4][2];
#pragma unroll
    for (int mf = 0; mf < 4; ++mf)
#pragma unroll
        for (int nf = 0; nf < 2; ++nf) acc[mf][nf] = (f32x4){0.f, 0.f, 0.f, 0.f};

    for (int kc = 0; kc < 4; ++kc) {
        __syncthreads();
#pragma unroll
        for (int i = 0; i < 6; ++i) {
            int s = tid + i * 256;
            if (s < 1296) {
                int pxs = s >> 2, q = s & 3;
                int r = pxs / 18, c = pxs - r * 18;
                int py = ty0 - 1 + r, px = tx0 - 1 + c;
                short8_t o;
#pragma unroll
                for (int e = 0; e < 8; ++e) o[e] = 0;
                if (py >= 0 && py < WINP && px >= 0 && px < WINP) {
                    size_t gpx = (size_t)py * WINP + px;
                    if (kc == 0) {
                        short8_t f0 = *(const short8_t*)&fscl[((size_t)k * 16384 + gpx) * 96 + q * 8];
                        const float* S = &Scl[gpx * 96 + q * 8];
#pragma unroll
                        for (int e = 0; e < 8; ++e)
                            o[e] = (short)f2bf(S[e] + 2.f * bf2f((unsigned short)f0[e]));
                    } else if (kc == 1) {
                        const unsigned short* fp = &fscl[((size_t)k * 16384 + gpx) * 96];
                        short8_t f0 = *(const short8_t*)&fp[q * 8];
                        short8_t f1 = *(const short8_t*)&fp[32 + q * 8];
                        const float* S = &Scl[gpx * 96 + 32 + q * 8];
#pragma unroll
                        for (int e = 0; e < 8; ++e)
                            o[e] = (short)f2bf(S[e] - bf2f((unsigned short)f0[e]) + bf2f((unsigned short)f1[e]));
                    } else if (kc == 2) {
                        const float* S = &Scl[gpx * 96 + 64 + q * 8];
#pragma unroll
                        for (int e = 0; e < 8; ++e) o[e] = (short)f2bf(S[e]);
                    } else {
                        if (q == 0) {
#pragma unroll
                            for (int ch = 0; ch < 3; ++ch)
                                o[ch] = (short)f2bf(x[(size_t)(k * 3 + ch) * IMG + (size_t)(y1 + py) * Ww + x1 + px]);
                        }
                    }
                }
                *(short8_t*)&s_a[(r * 18 + c) * 32 + q * 8] = o;
            }
        }
        {
            const unsigned short* src = WF + (size_t)(108 + (half * 4 + kc) * 18) * 512;
#pragma unroll
            for (int i = 0; i < 5; ++i) {
                int cch = tid + i * 256;
                if (cch < 1152)
                    *(short8_t*)&s_b[cch * 8] = *(const short8_t*)&src[cch * 8];
            }
        }
        __syncthreads();
#pragma unroll
        for (int tap = 0; tap < 9; ++tap) {
            int dy = tap / 3, dx = tap % 3;
            short8_t a[4];
#pragma unroll
            for (int mf = 0; mf < 4; ++mf)
                a[mf] = *(const short8_t*)&s_a[((w * 4 + mf + dy) * 18 + (l & 15) + dx) * 32 + (l >> 4) * 8];
#pragma unroll
            for (int nf = 0; nf < 2; ++nf) {
                short8_t bfr = *(const short8_t*)&s_b[((tap * 2 + nf) * 64 + l) * 8];
#pragma unroll
                for (int mf = 0; mf < 4; ++mf)
                    acc[mf][nf] = __builtin_amdgcn_mfma_f32_16x16x32_bf16(a[mf], bfr, acc[mf][nf], 0, 0, 0);
            }
        }
    }
    __syncthreads();
    unsigned short* s_t = s_a;
#pragma unroll
    for (int nf = 0; nf < 2; ++nf) {
        float bias = m1b[half * 32 + nf * 16 + (l & 15)];
#pragma unroll
        for (int mf = 0; mf < 4; ++mf) {
            int row = w * 4 + mf;
#pragma unroll
            for (int r = 0; r < 4; ++r) {
                int col = (l >> 4) * 4 + r;
                float v = acc[mf][nf][r] + bias;
                v = v >= 0.f ? v : 0.2f * v;
                s_t[(row * 16 + col) * 32 + nf * 16 + (l & 15)] = f2bf(v);
            }
        }
    }
    __syncthreads();
    {
        int row = tid >> 4, col = tid & 15;
        size_t gpx = (size_t)(ty0 + row) * WINP + tx0 + col;
        unsigned short* dst = h1cl + ((size_t)k * 16384 + gpx) * 64 + half * 32;
#pragma unroll
        for (int i = 0; i < 4; ++i)
            *(short8_t*)&dst[i * 8] = *(short8_t*)&s_t[tid * 32 + i * 8];
    }
}

// ---------------- merge2 MFMA ----------------
// grid (64, 12 = k*2+half). IC=64, 2 kchunks.
__global__ __launch_bounds__(256) void merge2_mfma(
    const unsigned short* __restrict__ h1cl, const unsigned short* __restrict__ WF,
    const float* __restrict__ m2b, unsigned short* __restrict__ h2cl)
{
    const int tid = threadIdx.x;
    const int l = tid & 63, w = tid >> 6;
    const int T = blockIdx.x;
    const int k = blockIdx.y >> 1, half = blockIdx.y & 1;
    const int ty0 = (T >> 3) * 16, tx0 = (T & 7) * 16;

    __shared__ __align__(16) unsigned short s_a[10368];
    __shared__ __align__(16) unsigned short s_b[9216];

    f32x4 acc[4][2];
#pragma unroll
    for (int mf = 0; mf < 4; ++mf)
#pragma unroll
        for (int nf = 0; nf < 2; ++nf) acc[mf][nf] = (f32x4){0.f, 0.f, 0.f, 0.f};

    const unsigned short* ink = h1cl + (size_t)k * 16384 * 64;

    for (int kc = 0; kc < 2; ++kc) {
        __syncthreads();
#pragma unroll
        for (int i = 0; i < 6; ++i) {
            int s = tid + i * 256;
            if (s < 1296) {
                int pxs = s >> 2, q = s & 3;
                int r = pxs / 18, c = pxs - r * 18;
                int py = ty0 - 1 + r, px = tx0 - 1 + c;
                short8_t o;
                if (py >= 0 && py < WINP && px >= 0 && px < WINP) {
                    o = *(const short8_t*)&ink[(size_t)(py * WINP + px) * 64 + kc * 32 + q * 8];
                } else {
#pragma unroll
                    for (int e = 0; e < 8; ++e) o[e] = 0;
                }
                *(short8_t*)&s_a[(r * 18 + c) * 32 + q * 8] = o;
            }
        }
        {
            const unsigned short* src = WF + (size_t)(252 + (half * 2 + kc) * 18) * 512;
#pragma unroll
            for (int i = 0; i < 5; ++i) {
                int cch = tid + i * 256;
                if (cch < 1152)
                    *(short8_t*)&s_b[cch * 8] = *(const short8_t*)&src[cch * 8];
            }
        }
        __syncthreads();
#pragma unroll
        for (int tap = 0; tap < 9; ++tap) {
            int dy = tap / 3, dx = tap % 3;
            short8_t a[4];
#pragma unroll
            for (int mf = 0; mf < 4; ++mf)
                a[mf] = *(const short8_t*)&s_a[((w * 4 + mf + dy) * 18 + (l & 15) + dx) * 32 + (l >> 4) * 8];
#pragma unroll
            for (int nf = 0; nf < 2; ++nf) {
                short8_t bfr = *(const short8_t*)&s_b[((tap * 2 + nf) * 64 + l) * 8];
#pragma unroll
                for (int mf = 0; mf < 4; ++mf)
                    acc[mf][nf] = __builtin_amdgcn_mfma_f32_16x16x32_bf16(a[mf], bfr, acc[mf][nf], 0, 0, 0);
            }
        }
    }
    __syncthreads();
    unsigned short* s_t = s_a;
#pragma unroll
    for (int nf = 0; nf < 2; ++nf) {
        float bias = m2b[half * 32 + nf * 16 + (l & 15)];
#pragma unroll
        for (int mf = 0; mf < 4; ++mf) {
            int row = w * 4 + mf;
#pragma unroll
            for (int r = 0; r < 4; ++r) {
                int col = (l >> 4) * 4 + r;
                s_t[(row * 16 + col) * 32 + nf * 16 + (l & 15)] = f2bf(acc[mf][nf][r] + bias);
            }
        }
    }
    __syncthreads();
    {
        int row = tid >> 4, col = tid & 15;
        size_t gpx = (size_t)(ty0 + row) * WINP + tx0 + col;
        unsigned short* dst = h2cl + ((size_t)k * 16384 + gpx) * 64 + half * 32;
#pragma unroll
        for (int i = 0; i < 4; ++i)
            *(short8_t*)&dst[i * 8] = *(short8_t*)&s_t[tid * 32 + i * 8];
    }
}

// ---------------- head MFMA + tanh + scatter ----------------
// grid (49 = 7x7 tiles over [10,118), 6 = k). NF=1 (16 oc, 3 real).
__global__ __launch_bounds__(256) void head_mfma(
    const unsigned short* __restrict__ h2cl, const unsigned short* __restrict__ WF,
    const float* __restrict__ hb, const int* __restrict__ box,
    float* __restrict__ out)
{
    const int tid = threadIdx.x;
    const int l = tid & 63, w = tid >> 6;
    const int T = blockIdx.x;
    const int k = blockIdx.y;
    const int oy0 = 10 + (T / 7) * 16, ox0 = 10 + (T % 7) * 16;
    const int y1 = box[0], x1 = box[1];

    __shared__ __align__(16) unsigned short s_a[10368];
    __shared__ __align__(16) unsigned short s_b[4608];

    f32x4 acc[4];
#pragma unroll
    for (int mf = 0; mf < 4; ++mf) acc[mf] = (f32x4){0.f, 0.f, 0.f, 0.f};

    const unsigned short* ink = h2cl + (size_t)k * 16384 * 64;

    for (int kc = 0; kc < 2; ++kc) {
        __syncthreads();
#pragma unroll
        for (int i = 0; i < 6; ++i) {
            int s = tid + i * 256;
            if (s < 1296) {
                int pxs = s >> 2, q = s & 3;
                int r = pxs / 18, c = pxs - r * 18;
                int py = oy0 - 1 + r, px = ox0 - 1 + c;   // always in [9,122] -> in bounds
                *(short8_t*)&s_a[(r * 18 + c) * 32 + q * 8] =
                    *(const short8_t*)&ink[(size_t)(py * WINP + px) * 64 + kc * 32 + q * 8];
            }
        }
        {
            const unsigned short* src = WF + (size_t)(324 + kc * 9) * 512;
#pragma unroll
            for (int i = 0; i < 3; ++i) {
                int cch = tid + i * 256;
                if (cch < 576)
                    *(short8_t*)&s_b[cch * 8] = *(const short8_t*)&src[cch * 8];
            }
        }
        __syncthreads();
#pragma unroll
        for (int tap = 0; tap < 9; ++tap) {
            int dy = tap / 3, dx = tap % 3;
            short8_t bfr = *(const short8_t*)&s_b[(tap * 64 + l) * 8];
#pragma unroll
            for (int mf = 0; mf < 4; ++mf) {
                short8_t a = *(const short8_t*)&s_a[((w * 4 + mf + dy) * 18 + (l & 15) + dx) * 32 + (l >> 4) * 8];
                acc[mf] = __builtin_amdgcn_mfma_f32_16x16x32_bf16(a, bfr, acc[mf], 0, 0, 0);
            }
        }
    }
    int oc = l & 15;
    if (oc < 3) {
        float bias = hb[oc];
#pragma unroll
        for (int mf = 0; mf < 4; ++mf) {
            int row = oy0 + w * 4 + mf;
            if (row < 118) {
#pragma unroll
                for (int r = 0; r < 4; ++r) {
                    int col = ox0 + (l >> 4) * 4 + r;
                    if (col < 118) {
                        float v = (tanhf(acc[mf][r] + bias) + 1.0f) * 0.5f;
                        out[(size_t)(k * 3 + oc) * IMG + (size_t)(y1 + row) * Ww + x1 + col] = v;
                    }
                }
            }
        }
    }
}

extern "C" void kernel_launch(void* const* d_in, const int* in_sizes, int n_in,
                              void* d_out, int out_size, void* d_ws, size_t ws_size,
                              hipStream_t stream)
{
    const float* x       = (const float*)d_in[0];
    const float* pred    = (const float*)d_in[1];
    const float* feat    = (const float*)d_in[2];
    const float* split_w = (const float*)d_in[3];
    const float* split_b = (const float*)d_in[4];
    const float* m1w     = (const float*)d_in[5];
    const float* m1b     = (const float*)d_in[6];
    const float* m2w     = (const float*)d_in[7];
    const float* m2b     = (const float*)d_in[8];
    const float* hw      = (const float*)d_in[9];
    const float* hb      = (const float*)d_in[10];
    float* out = (float*)d_out;

    char* base = (char*)d_ws;
    size_t o = 0;
    int* box = (int*)(base + o);                  o += 256;
    unsigned short* WF = (unsigned short*)(base + o);      o += (size_t)175104 * 2;  o = (o + 255) & ~(size_t)255;
    unsigned short* featcl = (unsigned short*)(base + o);  o += (size_t)6 * 16384 * 64 * 2;
    unsigned short* fscl = (unsigned short*)(base + o);    o += (size_t)6 * 16384 * 96 * 2;
    float* Scl = (float*)(base + o);                       o += (size_t)16384 * 96 * 4;
    unsigned short* h1cl = (unsigned short*)(base + o);    o += (size_t)6 * 16384 * 64 * 2;
    unsigned short* h2cl = (unsigned short*)(base + o);    o += (size_t)6 * 16384 * 64 * 2;

    box_kernel<<<1, 256, 0, stream>>>(pred, box);
    prep_weights<<<684, 256, 0, stream>>>(split_w, m1w, m2w, hw, WF);
    prep_featcl<<<dim3(128, 6), 256, 0, stream>>>(feat, box, featcl);
    copy_kernel<<<4608, 256, 0, stream>>>((const float4*)pred, (float4*)out);

    for (int it = 0; it < 2; ++it) {
        split_mfma<<<dim3(64, 18), 256, 0, stream>>>(featcl, out, WF, split_b, box, fscl);
        reduce_kernel<<<256, 256, 0, stream>>>(fscl, Scl);
        merge1_mfma<<<dim3(64, 12), 256, 0, stream>>>(fscl, Scl, x, WF, m1b, box, h1cl);
        merge2_mfma<<<dim3(64, 12), 256, 0, stream>>>(h1cl, WF, m2b, h2cl);
        head_mfma<<<dim3(49, 6), 256, 0, stream>>>(h2cl, WF, hb, box, out);
    }
}